// Round 13
// baseline (63.587 us; speedup 1.0000x reference)
//
#include <hip/hip_runtime.h>
#include <hip/hip_bf16.h>

#define N_CLS 4096
#define FDIM  2048
#define NT    16          // 16 K-tiles of BK=128 (fp8)

typedef float  floatx4 __attribute__((ext_vector_type(4)));
typedef int    intx2   __attribute__((ext_vector_type(2)));
typedef int    intx4   __attribute__((ext_vector_type(4)));
typedef int    intx8   __attribute__((ext_vector_type(8)));

// ---------------------------------------------------------------------------
// Kernel A: row norms, fp32 diag, fp8-e4m3 conversion; zeroes accum.
// ---------------------------------------------------------------------------
__global__ __launch_bounds__(256) void prep_kernel(
    const float* __restrict__ bnd,
    const float* __restrict__ proto,
    const float* __restrict__ wgt,
    unsigned char* __restrict__ pf8,
    unsigned char* __restrict__ wf8,
    float* __restrict__ t1,
    float* __restrict__ cc,
    float* __restrict__ accum)
{
    const int row = blockIdx.x;
    const int tid = threadIdx.x;
    const size_t base = (size_t)row * FDIM + (size_t)tid * 8;

    floatx4 p0 = *(const floatx4*)(proto + base);
    floatx4 p1 = *(const floatx4*)(proto + base + 4);
    floatx4 w0 = *(const floatx4*)(wgt + base);
    floatx4 w1 = *(const floatx4*)(wgt + base + 4);

    float ss = 0.f, dt = 0.f;
#pragma unroll
    for (int k = 0; k < 4; ++k) {
        ss += p0[k] * p0[k] + p1[k] * p1[k];
        dt += p0[k] * w0[k] + p1[k] * w1[k];
    }
#pragma unroll
    for (int off = 32; off > 0; off >>= 1) {
        ss += __shfl_down(ss, off);
        dt += __shfl_down(dt, off);
    }

    __shared__ float sss[4], sdt[4];
    __shared__ float srn;
    const int wid = tid >> 6, lane = tid & 63;
    if (lane == 0) { sss[wid] = ss; sdt[wid] = dt; }
    __syncthreads();
    if (tid == 0) {
        float SS = sss[0] + sss[1] + sss[2] + sss[3];
        float DT = sdt[0] + sdt[1] + sdt[2] + sdt[3];
        float rn = 1.0f / fmaxf(sqrtf(SS), 1e-12f);
        srn = rn;
        float bv = bnd[row];
        t1[row] = (1.0f - bv) * (DT * rn);   // (1-b_i)*diag_i, fp32 exact
        cc[row] = bv - 1.0f;
        if (row == 0) *accum = 0.0f;         // re-zero every launch
    }
    __syncthreads();
    const float rn = srn;

    intx2 pv, wv;
    {
        int a = __builtin_amdgcn_cvt_pk_fp8_f32(p0[0] * rn, p0[1] * rn, 0, 0);
        a     = __builtin_amdgcn_cvt_pk_fp8_f32(p0[2] * rn, p0[3] * rn, a, 1);
        int b = __builtin_amdgcn_cvt_pk_fp8_f32(p1[0] * rn, p1[1] * rn, 0, 0);
        b     = __builtin_amdgcn_cvt_pk_fp8_f32(p1[2] * rn, p1[3] * rn, b, 1);
        pv[0] = a; pv[1] = b;
        int c = __builtin_amdgcn_cvt_pk_fp8_f32(w0[0], w0[1], 0, 0);
        c     = __builtin_amdgcn_cvt_pk_fp8_f32(w0[2], w0[3], c, 1);
        int d = __builtin_amdgcn_cvt_pk_fp8_f32(w1[0], w1[1], 0, 0);
        d     = __builtin_amdgcn_cvt_pk_fp8_f32(w1[2], w1[3], d, 1);
        wv[0] = c; wv[1] = d;
    }
    *(intx2*)(pf8 + base) = pv;
    *(intx2*)(wf8 + base) = wv;
}

// ---------------------------------------------------------------------------
// Kernel B: MX-fp8 GEMM, 128x128 tile, 4 waves (2Mx2N), per-wave 64x64
// (acc[4][4] of 16x16), BK=128, 2x32KB LDS dbuf -> 2 BLOCKS/CU (m97/m114
// cross-block pipe overlap). Counted-vmcnt 4-phase schedule per K-tile:
//   stage plan for tile u+1 during tile u: P0:{Acall0,Acall2} P1:{Bcall0,
//   Bcall2} P2:{Bcall1,Bcall3} P3:{Acall1,Acall3}  (call c = 32 rows)
//   each overwrite lands >=4 barriers after that region's last read;
//   vmcnt = (4,4,4,-): floor of 4 loads in flight, never drained.
// sigma-permuted pair layout (R11-proven, 0 bank conflicts): pair p of row r
// at slot sigma(p)^(r&7); reads hit slots {q^r7,(4|q)^r7}.
// MFMA: mfma_scale_f32_16x16x128_f8f6f4 fmt=0 (e4m3), scale=2^0.
// ---------------------------------------------------------------------------
#define PH_BAR() { __builtin_amdgcn_s_barrier(); __builtin_amdgcn_sched_barrier(0); }
#define VMCNT(N) asm volatile("s_waitcnt vmcnt(" #N ")" ::: "memory")

#define RD_FA2(D, MI0)                                                         \
    _Pragma("unroll") for (int k = 0; k < 2; ++k) {                            \
        const unsigned char* bp = &sAB[D][aoff + ((MI0) + k) * 2048];          \
        intx4* fp = (intx4*)&fa[(MI0) + k];                                    \
        fp[0] = *(const intx4*)(bp + cq0);                                     \
        fp[1] = *(const intx4*)(bp + cq1);                                     \
    }
#define RD_FB2(D, NI0)                                                         \
    _Pragma("unroll") for (int k = 0; k < 2; ++k) {                            \
        const unsigned char* bp = &sAB[D][boff + ((NI0) + k) * 2048];          \
        intx4* fp = (intx4*)&fb[(NI0) + k];                                    \
        fp[0] = *(const intx4*)(bp + cq0);                                     \
        fp[1] = *(const intx4*)(bp + cq1);                                     \
    }
#define MFMA_Q2(MI0, NI0)                                                      \
    __builtin_amdgcn_s_setprio(1);                                             \
    _Pragma("unroll") for (int mi = 0; mi < 2; ++mi)                           \
    _Pragma("unroll") for (int ni = 0; ni < 2; ++ni)                           \
        acc[(MI0)+mi][(NI0)+ni] =                                              \
            __builtin_amdgcn_mfma_scale_f32_16x16x128_f8f6f4(                  \
                fa[(MI0)+mi], fb[(NI0)+ni], acc[(MI0)+mi][(NI0)+ni],           \
                0, 0, 0, SC1, 0, SC1);                                         \
    __builtin_amdgcn_s_setprio(0);

__global__ __launch_bounds__(256, 2) void gemm_reduce_kernel(
    const unsigned char* __restrict__ A,   // p_fp8 [4096][2048]
    const unsigned char* __restrict__ B,   // w_fp8 [4096][2048]
    const float* __restrict__ t1,
    const float* __restrict__ cc,
    float* __restrict__ accum)
{
    __shared__ unsigned char sAB[2][32768];  // per buf: A (16KB) | B (16KB)
    __shared__ float red[4];

    const int tid  = threadIdx.x;
    const int wid  = tid >> 6;
    const int lane = tid & 63;
    const int SC1  = 0x7F7F7F7F;   // e8m0 = 127 -> 2^0 for all 4 K-blocks

    // XCD-aware bijective swizzle: 1024 blocks over 32x32 tile grid
    // (R10-proven mapping).
    const int b   = blockIdx.x;
    const int xcd = b & 7, sl = b >> 3;              // sl 0..127
    const int bi  = ((xcd & 1) << 4) | (sl & 15);    // 0..31
    const int bj  = ((xcd >> 1) << 3) | (sl >> 4);   // 0..31
    const int arow0 = bi * 128;
    const int brow0 = bj * 128;

    const int wm = wid >> 1;   // 0..1 : 64-row strip
    const int wn = wid & 1;    // 0..1 : 64-col strip
    const int lr = lane & 15;
    const int q  = lane >> 4;  // k-quarter
    const int r7 = lane & 7;

    // sigma-permuted slots (R11-proven): logical pairs {2q,2q+1} at slots
    // {q^r7, (4|q)^r7}
    const int cq0 = ((q)     ^ r7) << 4;
    const int cq1 = ((4 | q) ^ r7) << 4;
    const int aoff = (wm * 64 + lr) * 128;           // A base in buf
    const int boff = 16384 + (wn * 64 + lr) * 128;   // B base in buf

    // staging: call c covers rows 32c..32c+31; thread t -> row 32c+(t>>3),
    // slot s = t&7; global pair p = sigma^-1(s ^ (row&7)).
    const int srow = tid >> 3;                       // 0..31
    const int sx   = (tid & 7) ^ ((tid >> 3) & 7);
    const int sgc  = (((sx & 3) << 1) | (sx >> 2)) << 4;

    auto glds = [&](const unsigned char* src, unsigned char* dst) {
        __builtin_amdgcn_global_load_lds(
            (const __attribute__((address_space(1))) void*)src,
            (__attribute__((address_space(3))) void*)dst, 16, 0, 0);
    };
    // stage A calls {pair, pair+2} (rows {32p..,64+32p..}) of tile t
    auto stageApair = [&](int pair, int t) {
#pragma unroll
        for (int h = 0; h < 2; ++h) {
            const int c = pair + 2 * h;              // call index 0..3
            glds(A + (size_t)(arow0 + c * 32 + srow) * FDIM + t * 128 + sgc,
                 &sAB[t & 1][c * 4096 + tid * 16]);
        }
    };
    auto stageBpair = [&](int pair, int t) {
#pragma unroll
        for (int h = 0; h < 2; ++h) {
            const int c = pair + 2 * h;
            glds(B + (size_t)(brow0 + c * 32 + srow) * FDIM + t * 128 + sgc,
                 &sAB[t & 1][16384 + c * 4096 + tid * 16]);
        }
    };

    floatx4 acc[4][4];
#pragma unroll
    for (int m = 0; m < 4; ++m)
#pragma unroll
        for (int n = 0; n < 4; ++n) acc[m][n] = (floatx4)0.0f;

    intx8 fa[4];   // A frags [mi] (32 B each)
    intx8 fb[4];   // B frags [ni]

    // ---- prologue: stage tile 0 in steady-state order (8 calls)
    stageApair(0, 0); stageBpair(0, 0); stageBpair(1, 0); stageApair(1, 0);

#pragma unroll 1
    for (int t = 0; t < NT; ++t) {
        const int D  = t & 1;
        const int tn = (t + 1 > NT - 1) ? NT - 2 : t + 1;  // parity-preserving

        // P0: rd fa01, fb01 | stage A02(t+1) | MFMA (0,0)
        VMCNT(4);
        PH_BAR();
        RD_FA2(D, 0); RD_FB2(D, 0);
        stageApair(0, tn);
        MFMA_Q2(0, 0);
        // P1: rd fb23 | stage B02(t+1) | MFMA (0,2)
        VMCNT(4);
        PH_BAR();
        RD_FB2(D, 2);
        stageBpair(0, tn);
        MFMA_Q2(0, 2);
        // P2: rd fa23 | stage B13(t+1) | MFMA (2,2)
        VMCNT(4);
        PH_BAR();
        RD_FA2(D, 2);
        stageBpair(1, tn);
        MFMA_Q2(2, 2);
        // P3: stage A13(t+1) | MFMA (2,0)
        PH_BAR();
        stageApair(1, tn);
        MFMA_Q2(2, 0);
    }

    // ---- epilogue: val = relu(t1[i] + s_ij*c[j]), skip i==j, global sum.
    // C/D layout (shape-determined): col = lane&15, row = (lane>>4)*4 + reg.
    const int row0 = arow0 + wm * 64 + (lane >> 4) * 4;
    const int col0 = brow0 + wn * 64 + lr;

    float local = 0.f;
#pragma unroll
    for (int n = 0; n < 4; ++n) {
        const int j = col0 + n * 16;
        const float cj = cc[j];
#pragma unroll
        for (int m = 0; m < 4; ++m) {
#pragma unroll
            for (int r = 0; r < 4; ++r) {
                const int i = row0 + m * 16 + r;
                float v = fmaxf(t1[i] + acc[m][n][r] * cj, 0.f);
                local += (i == j) ? 0.f : v;
            }
        }
    }

#pragma unroll
    for (int off = 32; off > 0; off >>= 1)
        local += __shfl_down(local, off);
    if (lane == 0) red[wid] = local;
    __syncthreads();
    if (tid == 0)
        atomicAdd(accum, red[0] + red[1] + red[2] + red[3]);
}

__global__ void finalize_kernel(const float* __restrict__ accum,
                                float* __restrict__ out)
{
    const float denom = 4096.0f * 4095.0f;  // exact in fp32
    out[0] = *accum / denom;
}

extern "C" void kernel_launch(void* const* d_in, const int* in_sizes, int n_in,
                              void* d_out, int out_size, void* d_ws, size_t ws_size,
                              hipStream_t stream) {
    const float* bnd   = (const float*)d_in[0];
    const float* proto = (const float*)d_in[1];
    const float* wgt   = (const float*)d_in[2];

    char* ws = (char*)d_ws;
    unsigned char* pf8 = (unsigned char*)ws;                               // 8 MB
    unsigned char* wf8 = (unsigned char*)(ws + (size_t)N_CLS * FDIM);      // 8 MB
    float* t1    = (float*)(ws + (size_t)N_CLS * FDIM * 2);
    float* cc    = t1 + N_CLS;
    float* accum = cc + N_CLS;

    prep_kernel<<<N_CLS, 256, 0, stream>>>(bnd, proto, wgt, pf8, wf8, t1, cc, accum);
    gemm_reduce_kernel<<<1024, 256, 0, stream>>>(pf8, wf8, t1, cc, accum);
    finalize_kernel<<<1, 1, 0, stream>>>(accum, (float*)d_out);
}

// Round 14
// 53.024 us; speedup vs baseline: 1.1992x; 1.1992x over previous
//
#include <hip/hip_runtime.h>
#include <hip/hip_bf16.h>

#define N_CLS 4096
#define FDIM  2048
#define NT    16          // 16 K-tiles of BK=128 (fp8)

typedef float  floatx4 __attribute__((ext_vector_type(4)));
typedef int    intx2   __attribute__((ext_vector_type(2)));
typedef int    intx4   __attribute__((ext_vector_type(4)));
typedef int    intx8   __attribute__((ext_vector_type(8)));

// ---------------------------------------------------------------------------
// Kernel A: row norms, fp32 diag, fp8-e4m3 conversion; zeroes accum.
// ---------------------------------------------------------------------------
__global__ __launch_bounds__(256) void prep_kernel(
    const float* __restrict__ bnd,
    const float* __restrict__ proto,
    const float* __restrict__ wgt,
    unsigned char* __restrict__ pf8,
    unsigned char* __restrict__ wf8,
    float* __restrict__ t1,
    float* __restrict__ cc,
    float* __restrict__ accum)
{
    const int row = blockIdx.x;
    const int tid = threadIdx.x;
    const size_t base = (size_t)row * FDIM + (size_t)tid * 8;

    floatx4 p0 = *(const floatx4*)(proto + base);
    floatx4 p1 = *(const floatx4*)(proto + base + 4);
    floatx4 w0 = *(const floatx4*)(wgt + base);
    floatx4 w1 = *(const floatx4*)(wgt + base + 4);

    float ss = 0.f, dt = 0.f;
#pragma unroll
    for (int k = 0; k < 4; ++k) {
        ss += p0[k] * p0[k] + p1[k] * p1[k];
        dt += p0[k] * w0[k] + p1[k] * w1[k];
    }
#pragma unroll
    for (int off = 32; off > 0; off >>= 1) {
        ss += __shfl_down(ss, off);
        dt += __shfl_down(dt, off);
    }

    __shared__ float sss[4], sdt[4];
    __shared__ float srn;
    const int wid = tid >> 6, lane = tid & 63;
    if (lane == 0) { sss[wid] = ss; sdt[wid] = dt; }
    __syncthreads();
    if (tid == 0) {
        float SS = sss[0] + sss[1] + sss[2] + sss[3];
        float DT = sdt[0] + sdt[1] + sdt[2] + sdt[3];
        float rn = 1.0f / fmaxf(sqrtf(SS), 1e-12f);
        srn = rn;
        float bv = bnd[row];
        t1[row] = (1.0f - bv) * (DT * rn);   // (1-b_i)*diag_i, fp32 exact
        cc[row] = bv - 1.0f;
        if (row == 0) *accum = 0.0f;         // re-zero every launch
    }
    __syncthreads();
    const float rn = srn;

    intx2 pv, wv;
    {
        int a = __builtin_amdgcn_cvt_pk_fp8_f32(p0[0] * rn, p0[1] * rn, 0, 0);
        a     = __builtin_amdgcn_cvt_pk_fp8_f32(p0[2] * rn, p0[3] * rn, a, 1);
        int b = __builtin_amdgcn_cvt_pk_fp8_f32(p1[0] * rn, p1[1] * rn, 0, 0);
        b     = __builtin_amdgcn_cvt_pk_fp8_f32(p1[2] * rn, p1[3] * rn, b, 1);
        pv[0] = a; pv[1] = b;
        int c = __builtin_amdgcn_cvt_pk_fp8_f32(w0[0], w0[1], 0, 0);
        c     = __builtin_amdgcn_cvt_pk_fp8_f32(w0[2], w0[3], c, 1);
        int d = __builtin_amdgcn_cvt_pk_fp8_f32(w1[0], w1[1], 0, 0);
        d     = __builtin_amdgcn_cvt_pk_fp8_f32(w1[2], w1[3], d, 1);
        wv[0] = c; wv[1] = d;
    }
    *(intx2*)(pf8 + base) = pv;
    *(intx2*)(wf8 + base) = wv;
}

// ---------------------------------------------------------------------------
// Kernel B: MX-fp8 GEMM, ONE barrier + ONE vmcnt(0) per K-tile (m97-style
// single-sync structure at the R11 geometry). Per K-tile body:
//   { vmcnt(0); s_barrier; sched_barrier;
//     stage all 4 regions of tile t+1 (8 global_load_lds);
//     read frags + 32 MFMAs (compiler's fine-grained lgkmcnt interleaves) }
// Rationale (R11 audit): 4-barriers+3-vmcnt per tile cost ~2500 cyc/tile of
// convoy overhead (~40% of runtime). Stages issue at body top -> by next
// tile's vmcnt(0) they had ~5000 cyc to land (HBM latency fully hidden).
// Safety: stages (buffer D^1) issue only after the barrier; every wave's
// reads of D^1 completed before its barrier arrival (lgkm drained by its
// own MFMAs, program order). 17 barriers total vs 66.
// BM=BN=256, BK=128 fp8, 8 waves (2Mx4N), per-wave 128x64, acc[8][4].
// sigma-permuted pair layout (R11-proven, 0 bank conflicts).
// MFMA: mfma_scale_f32_16x16x128_f8f6f4 fmt=0 (e4m3), scale=2^0.
// ---------------------------------------------------------------------------
#define PH_BAR() { __builtin_amdgcn_s_barrier(); __builtin_amdgcn_sched_barrier(0); }
#define VMCNT(N) asm volatile("s_waitcnt vmcnt(" #N ")" ::: "memory")

#define RD_FA(D, MH)                                                           \
    _Pragma("unroll") for (int mi = 0; mi < 4; ++mi) {                         \
        const unsigned char* bp = &sAB[D][aoff + ((MH)*64 + mi*16) * 128];     \
        intx4* fp = (intx4*)&fa[mi];                                           \
        fp[0] = *(const intx4*)(bp + cq0);                                     \
        fp[1] = *(const intx4*)(bp + cq1);                                     \
    }
#define RD_FB2(D, NI0)                                                         \
    _Pragma("unroll") for (int ni = 0; ni < 2; ++ni) {                         \
        const unsigned char* bp = &sAB[D][boff + ((NI0)+ni) * 2048];           \
        intx4* fp = (intx4*)&fb[(NI0)+ni];                                     \
        fp[0] = *(const intx4*)(bp + cq0);                                     \
        fp[1] = *(const intx4*)(bp + cq1);                                     \
    }
#define MFMA_Q(MI0, NI0)                                                       \
    __builtin_amdgcn_s_setprio(1);                                             \
    _Pragma("unroll") for (int mi = 0; mi < 4; ++mi)                           \
    _Pragma("unroll") for (int ni = 0; ni < 2; ++ni)                           \
        acc[(MI0)+mi][(NI0)+ni] =                                              \
            __builtin_amdgcn_mfma_scale_f32_16x16x128_f8f6f4(                  \
                fa[mi], fb[(NI0)+ni], acc[(MI0)+mi][(NI0)+ni],                 \
                0, 0, 0, SC1, 0, SC1);                                         \
    __builtin_amdgcn_s_setprio(0);

__global__ __launch_bounds__(512, 1) void gemm_reduce_kernel(
    const unsigned char* __restrict__ A,   // p_fp8 [4096][2048]
    const unsigned char* __restrict__ B,   // w_fp8 [4096][2048]
    const float* __restrict__ t1,
    const float* __restrict__ cc,
    float* __restrict__ accum)
{
    __shared__ unsigned char sAB[2][65536];  // per buf: A0|A1|B0|B1, 16KB each
    __shared__ float red[8];

    const int tid  = threadIdx.x;
    const int wid  = tid >> 6;
    const int lane = tid & 63;
    const int SC1  = 0x7F7F7F7F;   // e8m0 = 127 -> 2^0 for all 4 K-blocks

    // XCD-aware bijective swizzle: 256 blocks over 16x16 tile grid.
    const int b   = blockIdx.x;
    const int xcd = b & 7, sl = b >> 3;
    const int bi  = ((xcd & 3) << 2) + (sl & 3);
    const int bj  = ((xcd >> 2) << 3) + (sl >> 2);
    const int arow0 = bi * 256;
    const int brow0 = bj * 256;

    const int wm = wid >> 2;   // 0..1 : 128-row strip
    const int wn = wid & 3;    // 0..3 : 64-col strip
    const int lr = lane & 15;
    const int q  = lane >> 4;  // k-quarter: logical pairs {2q, 2q+1}
    const int r7 = lane & 7;

    // sigma-permuted slots: pair 2q -> slot q^r7; pair 2q+1 -> slot (4|q)^r7
    const int cq0 = ((q)     ^ r7) << 4;
    const int cq1 = ((4 | q) ^ r7) << 4;
    // frag base byte offsets within a buffer:
    const int aoff = wm * 16384 + lr * 128;
    const int boff = 32768 + (wn >> 1) * 16384 + (wn & 1) * 8192 + lr * 128;

    // staging: thread t writes rows {t>>3, 64+(t>>3)}, LDS slot s = t&7;
    // global source pair p = sigma^-1(s ^ (row&7)), sigma^-1(x)=((x&3)<<1)|(x>>2).
    const int srow = tid >> 3;
    const int sx   = (tid & 7) ^ ((tid >> 3) & 7);
    const int sgc  = (((sx & 3) << 1) | (sx >> 2)) << 4;

    auto glds = [&](const unsigned char* src, unsigned char* dst) {
        __builtin_amdgcn_global_load_lds(
            (const __attribute__((address_space(1))) void*)src,
            (__attribute__((address_space(3))) void*)dst, 16, 0, 0);
    };
    auto stageA = [&](int h, int t) {
        unsigned char* dst = &sAB[t & 1][h * 16384 + tid * 16];
        const unsigned char* src =
            A + (size_t)(arow0 + h * 128 + srow) * FDIM + t * 128 + sgc;
        glds(src, dst);
        glds(src + (size_t)64 * FDIM, dst + 8192);
    };
    auto stageB = [&](int h, int t) {
        unsigned char* dst = &sAB[t & 1][32768 + h * 16384 + tid * 16];
        const unsigned char* src =
            B + (size_t)(brow0 + h * 128 + srow) * FDIM + t * 128 + sgc;
        glds(src, dst);
        glds(src + (size_t)64 * FDIM, dst + 8192);
    };

    floatx4 acc[8][4];
#pragma unroll
    for (int m = 0; m < 8; ++m)
#pragma unroll
        for (int n = 0; n < 4; ++n) acc[m][n] = (floatx4)0.0f;

    intx8 fa[4];   // current A-half frags [mi] (32 B each)
    intx8 fb[4];   // B frags for current tile [ni]

    // ---- prologue: stage tile 0 (8 loads); drained by t=0's vmcnt(0)
    stageA(0, 0); stageA(1, 0); stageB(0, 0); stageB(1, 0);

#pragma unroll 1
    for (int t = 0; t < NT; ++t) {
        const int D = t & 1;

        VMCNT(0);        // tile t fully landed (issued one full body ago)
        PH_BAR();        // all waves' reads of buffer D^1 are complete

        // stage tile t+1 into buffer D^1 (uniform branch, no divergence)
        if (t + 1 < NT) {
            stageA(0, t + 1); stageA(1, t + 1);
            stageB(0, t + 1); stageB(1, t + 1);
        }

        // compute tile t from buffer D; compiler interleaves via lgkmcnt
        RD_FA(D, 0);
        RD_FB2(D, 0); RD_FB2(D, 2);
        MFMA_Q(0, 0); MFMA_Q(0, 2);
        RD_FA(D, 1);                  // fa reuse: per-wave scoreboard (m97)
        MFMA_Q(4, 0); MFMA_Q(4, 2);
    }

    // ---- epilogue: val = relu(t1[i] + s_ij*c[j]), skip i==j, global sum.
    // C/D layout (shape-determined): col = lane&15, row = (lane>>4)*4 + reg.
    const int row0 = arow0 + wm * 128 + (lane >> 4) * 4;
    const int col0 = brow0 + wn * 64 + lr;

    float local = 0.f;
#pragma unroll
    for (int n = 0; n < 4; ++n) {
        const int j = col0 + n * 16;
        const float cj = cc[j];
#pragma unroll
        for (int m = 0; m < 8; ++m) {
#pragma unroll
            for (int r = 0; r < 4; ++r) {
                const int i = row0 + m * 16 + r;
                float v = fmaxf(t1[i] + acc[m][n][r] * cj, 0.f);
                local += (i == j) ? 0.f : v;
            }
        }
    }

#pragma unroll
    for (int off = 32; off > 0; off >>= 1)
        local += __shfl_down(local, off);
    if (lane == 0) red[wid] = local;
    __syncthreads();
    if (tid == 0) {
        float s = 0.f;
#pragma unroll
        for (int w = 0; w < 8; ++w) s += red[w];
        atomicAdd(accum, s);
    }
}

__global__ void finalize_kernel(const float* __restrict__ accum,
                                float* __restrict__ out)
{
    const float denom = 4096.0f * 4095.0f;  // exact in fp32
    out[0] = *accum / denom;
}

extern "C" void kernel_launch(void* const* d_in, const int* in_sizes, int n_in,
                              void* d_out, int out_size, void* d_ws, size_t ws_size,
                              hipStream_t stream) {
    const float* bnd   = (const float*)d_in[0];
    const float* proto = (const float*)d_in[1];
    const float* wgt   = (const float*)d_in[2];

    char* ws = (char*)d_ws;
    unsigned char* pf8 = (unsigned char*)ws;                               // 8 MB
    unsigned char* wf8 = (unsigned char*)(ws + (size_t)N_CLS * FDIM);      // 8 MB
    float* t1    = (float*)(ws + (size_t)N_CLS * FDIM * 2);
    float* cc    = t1 + N_CLS;
    float* accum = cc + N_CLS;

    prep_kernel<<<N_CLS, 256, 0, stream>>>(bnd, proto, wgt, pf8, wf8, t1, cc, accum);
    gemm_reduce_kernel<<<256, 512, 0, stream>>>(pf8, wf8, t1, cc, accum);
    finalize_kernel<<<1, 1, 0, stream>>>(accum, (float*)d_out);
}